// Round 5
// baseline (2077.492 us; speedup 1.0000x reference)
//
#include <hip/hip_runtime.h>
#include <math.h>
#include <stdint.h>

// Problem dims
#define NB 16384    // batch
#define NH 768      // hidden
#define ND 784      // input features
#define NC 10       // classes
#define NW 12       // u64 words per 768-bit row

// ---------------------------------------------------------------------------
// prep: BN params in FAITHFUL f32 (replicating np op-by-op):
// sc = g * (1 / sqrt(v + 1e-5)), each op f32-rounded. [0]=sc,[1]=m,[2]=be,[3]=bias
// ---------------------------------------------------------------------------
__global__ void k_bnprep_f32(const float* __restrict__ g, const float* __restrict__ be,
                             const float* __restrict__ m, const float* __restrict__ v,
                             const float* __restrict__ bias, float* __restrict__ out) {
    int i = blockIdx.x * 256 + threadIdx.x;
    if (i >= NH) return;
    float t1 = __fadd_rn(v[i], 1e-5f);
    float t2 = __fsqrt_rn(t1);
    float t3 = __fdiv_rn(1.0f, t2);
    out[i]          = __fmul_rn(g[i], t3);
    out[NH + i]     = m[i];
    out[2 * NH + i] = be[i];
    out[3 * NH + i] = bias[i];
}

// ---------------------------------------------------------------------------
// prep: W1 signs as i8 +/-1, row-major (col, k): w1b[col*784 + k]
// ---------------------------------------------------------------------------
__global__ void k_pack_w1(const float* __restrict__ W1, int8_t* __restrict__ w1b) {
    int k = blockIdx.x * 256 + threadIdx.x;
    int col = blockIdx.y;
    if (k >= ND) return;
    float v = W1[(size_t)col * ND + k];
    w1b[(size_t)col * ND + k] = (v >= 0.0f) ? (int8_t)1 : (int8_t)-1;
}

// ---------------------------------------------------------------------------
// prep: W2/W3 sign bits, transposed words: wT[j*768 + col] bit l = (W[col][j*64+l] >= 0)
// ---------------------------------------------------------------------------
__global__ void k_pack_wT(const float* __restrict__ W, unsigned long long* __restrict__ wT) {
    int idx = blockIdx.x * 256 + threadIdx.x;
    if (idx >= NH * NW) return;
    int col = idx / NW, j = idx % NW;
    unsigned long long w = 0ull;
    for (int l = 0; l < 64; ++l) {
        float v = W[(size_t)col * NH + j * 64 + l];
        w |= (unsigned long long)(v >= 0.0f ? 1 : 0) << l;
    }
    wT[(size_t)j * NH + col] = w;
}

// ---------------------------------------------------------------------------
// GEMM1 replicating numpy einsum sum_of_products_contig_two (AVX512 npyv):
//   4 strided 16-lane FMA accumulator groups over k (main loop: 64/iter, 12 iters),
//   one extra 16-wide step (k=768..783) into group 0, combine (a0+a1)+(a2+a3)
//   lane-wise, then horizontal tree: (i,i+8) -> (i,i+4) -> (i,i+2) -> (0,1).
// Epilogue: +b1 (f32 add), BN f32 op-by-op, sign -> packed bits.
// One thread per output element; wave lanes = 64 consecutive cols of one row.
// ---------------------------------------------------------------------------
__global__ __launch_bounds__(256)
void k_gemm1_einsum(const float* __restrict__ x, const int8_t* __restrict__ w1b,
                    const float* __restrict__ bnp,
                    unsigned long long* __restrict__ s1p) {
    int g = blockIdx.x * 256 + threadIdx.x;   // 0 .. NB*NH-1
    int row = g / NH;
    int col = g % NH;
    int chunk = (col >> 6);
    const float* xr = x + (size_t)row * ND;
    const int8_t* wr = w1b + (size_t)col * ND;

    float a0[16], a1[16], a2[16], a3[16];
#pragma unroll
    for (int i = 0; i < 16; ++i) { a0[i] = 0.0f; a1[i] = 0.0f; a2[i] = 0.0f; a3[i] = 0.0f; }

    // main loop: 12 iterations of 64 (k = 0..767)
    for (int t = 0; t < 12; ++t) {
        int k0 = t * 64;
#pragma unroll
        for (int i = 0; i < 16; ++i) {
            a0[i] = __fmaf_rn((float)wr[k0 + i],      xr[k0 + i],      a0[i]);
            a1[i] = __fmaf_rn((float)wr[k0 + 16 + i], xr[k0 + 16 + i], a1[i]);
            a2[i] = __fmaf_rn((float)wr[k0 + 32 + i], xr[k0 + 32 + i], a2[i]);
            a3[i] = __fmaf_rn((float)wr[k0 + 48 + i], xr[k0 + 48 + i], a3[i]);
        }
    }
    // single-vector step: k = 768..783 into group 0
#pragma unroll
    for (int i = 0; i < 16; ++i)
        a0[i] = __fmaf_rn((float)wr[768 + i], xr[768 + i], a0[i]);

    // combine: (a0+a1)+(a2+a3) lane-wise
    float v[16];
#pragma unroll
    for (int i = 0; i < 16; ++i)
        v[i] = __fadd_rn(__fadd_rn(a0[i], a1[i]), __fadd_rn(a2[i], a3[i]));
    // horizontal tree (npyv_sum_f32 / _mm512_reduce_add_ps shape)
    float h8[8], h4[4], h2[2];
#pragma unroll
    for (int i = 0; i < 8; ++i) h8[i] = __fadd_rn(v[i], v[i + 8]);
#pragma unroll
    for (int i = 0; i < 4; ++i) h4[i] = __fadd_rn(h8[i], h8[i + 4]);
#pragma unroll
    for (int i = 0; i < 2; ++i) h2[i] = __fadd_rn(h4[i], h4[i + 2]);
    float acc = __fadd_rn(h2[0], h2[1]);

    // epilogue: + b1, BN1 f32 op-by-op, sign
    const float sc = bnp[col], mm = bnp[NH + col], be = bnp[2 * NH + col],
                bias = bnp[3 * NH + col];
    float h  = __fadd_rn(acc, bias);
    float t1 = __fsub_rn(h, mm);
    float u  = __fmul_rn(t1, sc);
    float hb = __fadd_rn(u, be);
    unsigned long long word = __ballot(hb >= 0.0f);
    if ((threadIdx.x & 63) == 0)
        s1p[(size_t)row * NW + chunk] = word;
}

// ---------------------------------------------------------------------------
// Binary layers 2/3: dot = 768 - 2*popcount(a XOR w) — exact integer, matches
// any-order f32 evaluation of +/-1 GEMM bit-for-bit (all partials exact).
// Epilogue faithful f32: h = fl(dot + b), BN op-by-op.
// MODE 0: sign -> packed bits. MODE 1: hardtanh -> f32 out.
// ---------------------------------------------------------------------------
template <int MODE>
__global__ __launch_bounds__(256, 2)
void k_popbin(const unsigned long long* __restrict__ Ap,
              const unsigned long long* __restrict__ wT,
              const float* __restrict__ bnp,
              unsigned long long* __restrict__ Sp, float* __restrict__ h_out) {
    __shared__ unsigned long long as[64][NW];
    const int tid = threadIdx.x;
    const int b0 = blockIdx.x * 64;

    for (int i = tid; i < 64 * NW; i += 256)
        as[i / NW][i % NW] = Ap[(size_t)(b0 + i / NW) * NW + i % NW];
    __syncthreads();

    const int wave = tid >> 6, lane = tid & 63;

    for (int chunk = 0; chunk < NW; ++chunk) {
        const int col = chunk * 64 + lane;
        unsigned long long w[NW];
#pragma unroll
        for (int j = 0; j < NW; ++j) w[j] = wT[(size_t)j * NH + col];
        const float sc = bnp[col], mm = bnp[NH + col], be = bnp[2 * NH + col],
                    bias = bnp[3 * NH + col];
        for (int r = 0; r < 16; ++r) {
            const int row = wave * 16 + r;
            int d = 0;
#pragma unroll
            for (int j = 0; j < NW; ++j)
                d += __builtin_popcountll(as[row][j] ^ w[j]);
            int dot = NH - 2 * d;
            float h  = __fadd_rn((float)dot, bias);
            float t  = __fsub_rn(h, mm);
            float u  = __fmul_rn(t, sc);
            float hb = __fadd_rn(u, be);
            if (MODE == 0) {
                unsigned long long word = __ballot(hb >= 0.0f);
                if (lane == 0) Sp[(size_t)(b0 + row) * NW + chunk] = word;
            } else {
                float hc = fminf(fmaxf(hb, -1.0f), 1.0f);
                h_out[(size_t)(b0 + row) * NH + col] = hc;
            }
        }
    }
}

// ---------------------------------------------------------------------------
// fc4 + log_softmax: one wave per row, double accumulation + shuffle reduce
// (no binarization downstream; 1e-6-level diffs vs f32 ref are far under threshold)
// ---------------------------------------------------------------------------
__global__ __launch_bounds__(256, 4)
void k_fc4(const float* __restrict__ h3, const float* __restrict__ W4,
           const float* __restrict__ b4, float* __restrict__ out) {
    __shared__ float w4s[NC * NH];
    const int tid = threadIdx.x;
    for (int i = tid; i < NC * NH; i += 256) w4s[i] = W4[i];
    __syncthreads();

    const int wave = tid >> 6, lane = tid & 63;
    const int row = blockIdx.x * 4 + wave;
    const float* hrow = h3 + (size_t)row * NH;

    double p[NC];
#pragma unroll
    for (int c = 0; c < NC; ++c) p[c] = 0.0;

    for (int it = 0; it < NH / 64; ++it) {
        int j = it * 64 + lane;
        double hv = (double)hrow[j];
#pragma unroll
        for (int c = 0; c < NC; ++c) p[c] += hv * (double)w4s[c * NH + j];
    }
#pragma unroll
    for (int c = 0; c < NC; ++c) {
#pragma unroll
        for (int off = 32; off > 0; off >>= 1) p[c] += __shfl_xor(p[c], off, 64);
    }
    double lg[NC];
    double mx = -1e300;
#pragma unroll
    for (int c = 0; c < NC; ++c) {
        lg[c] = p[c] + (double)b4[c];
        mx = fmax(mx, lg[c]);
    }
    double s = 0.0;
#pragma unroll
    for (int c = 0; c < NC; ++c) s += exp(lg[c] - mx);
    double lse = mx + log(s);
    if (lane < NC) {
        double v = 0.0;
#pragma unroll
        for (int c = 0; c < NC; ++c)
            if (lane == c) v = lg[c];
        out[(size_t)row * NC + lane] = (float)(v - lse);
    }
}

// ---------------------------------------------------------------------------
// launch
// ---------------------------------------------------------------------------
extern "C" void kernel_launch(void* const* d_in, const int* in_sizes, int n_in,
                              void* d_out, int out_size, void* d_ws, size_t ws_size,
                              hipStream_t stream) {
    const float* x  = (const float*)d_in[0];
    const float* W1 = (const float*)d_in[1];
    const float* b1 = (const float*)d_in[2];
    const float* W2 = (const float*)d_in[3];
    const float* b2 = (const float*)d_in[4];
    const float* W3 = (const float*)d_in[5];
    const float* b3 = (const float*)d_in[6];
    const float* W4 = (const float*)d_in[7];
    const float* b4 = (const float*)d_in[8];
    const float* g1 = (const float*)d_in[9],  *be1 = (const float*)d_in[10];
    const float* m1 = (const float*)d_in[11], *v1  = (const float*)d_in[12];
    const float* g2 = (const float*)d_in[13], *be2 = (const float*)d_in[14];
    const float* m2 = (const float*)d_in[15], *v2  = (const float*)d_in[16];
    const float* g3 = (const float*)d_in[17], *be3 = (const float*)d_in[18];
    const float* m3 = (const float*)d_in[19], *v3  = (const float*)d_in[20];
    float* out = (float*)d_out;

    char* ws = (char*)d_ws;
    size_t off = 0;
    int8_t* w1b = (int8_t*)(ws + off);              off += (size_t)NH * ND;           // 602,112
    unsigned long long* w2pT = (unsigned long long*)(ws + off); off += (size_t)NW * NH * 8;  // 73,728
    unsigned long long* w3pT = (unsigned long long*)(ws + off); off += (size_t)NW * NH * 8;
    unsigned long long* s1p  = (unsigned long long*)(ws + off); off += (size_t)NB * NW * 8;  // 1,572,864
    unsigned long long* s2p  = (unsigned long long*)(ws + off); off += (size_t)NB * NW * 8;
    float*  h3   = (float*)(ws + off);              off += (size_t)NB * NH * 4;       // 50,331,648
    float* bnp1 = (float*)(ws + off);               off += (size_t)4 * NH * 4;
    float* bnp2 = (float*)(ws + off);               off += (size_t)4 * NH * 4;
    float* bnp3 = (float*)(ws + off);               off += (size_t)4 * NH * 4;
    (void)ws_size; (void)in_sizes; (void)n_in; (void)out_size;

    // prep
    k_pack_w1<<<dim3(4, NH), 256, 0, stream>>>(W1, w1b);
    k_pack_wT<<<dim3((NH * NW + 255) / 256), 256, 0, stream>>>(W2, w2pT);
    k_pack_wT<<<dim3((NH * NW + 255) / 256), 256, 0, stream>>>(W3, w3pT);
    k_bnprep_f32<<<dim3(3), 256, 0, stream>>>(g1, be1, m1, v1, b1, bnp1);
    k_bnprep_f32<<<dim3(3), 256, 0, stream>>>(g2, be2, m2, v2, b2, bnp2);
    k_bnprep_f32<<<dim3(3), 256, 0, stream>>>(g3, be3, m3, v3, b3, bnp3);

    // layers
    k_gemm1_einsum<<<dim3((size_t)NB * NH / 256), 256, 0, stream>>>(x, w1b, bnp1, s1p);
    k_popbin<0><<<dim3(NB / 64), 256, 0, stream>>>(s1p, w2pT, bnp2, s2p, nullptr);
    k_popbin<1><<<dim3(NB / 64), 256, 0, stream>>>(s2p, w3pT, bnp3, nullptr, h3);
    k_fc4<<<dim3(NB / 4), 256, 0, stream>>>(h3, W4, b4, out);
}

// Round 6
// 1444.623 us; speedup vs baseline: 1.4381x; 1.4381x over previous
//
#include <hip/hip_runtime.h>
#include <math.h>
#include <stdint.h>

// Problem dims
#define NB 16384    // batch
#define NH 768      // hidden
#define ND 784      // input features
#define NC 10       // classes
#define NW 12       // u64 words per 768-bit row

// ---------------------------------------------------------------------------
// prep: BN params in FAITHFUL f32 (replicating np op-by-op):
// sc = g * (1 / sqrt(v + 1e-5)), each op f32-rounded. [0]=sc,[1]=m,[2]=be,[3]=bias
// ---------------------------------------------------------------------------
__global__ void k_bnprep_f32(const float* __restrict__ g, const float* __restrict__ be,
                             const float* __restrict__ m, const float* __restrict__ v,
                             const float* __restrict__ bias, float* __restrict__ out) {
    int i = blockIdx.x * 256 + threadIdx.x;
    if (i >= NH) return;
    float t1 = __fadd_rn(v[i], 1e-5f);
    float t2 = __fsqrt_rn(t1);
    float t3 = __fdiv_rn(1.0f, t2);
    out[i]          = __fmul_rn(g[i], t3);
    out[NH + i]     = m[i];
    out[2 * NH + i] = be[i];
    out[3 * NH + i] = bias[i];
}

// ---------------------------------------------------------------------------
// prep: W1 signs as bf16 +/-1 bit patterns (0x3F80 / 0xBF80), row-major [col][k]
// ---------------------------------------------------------------------------
__global__ void k_pack_w1bf(const float* __restrict__ W1, unsigned short* __restrict__ wbf) {
    int k = blockIdx.x * 256 + threadIdx.x;
    int col = blockIdx.y;
    if (k >= ND) return;
    float v = W1[(size_t)col * ND + k];
    wbf[(size_t)col * ND + k] = (v >= 0.0f) ? (unsigned short)0x3F80 : (unsigned short)0xBF80;
}

// ---------------------------------------------------------------------------
// prep: W2/W3 sign bits, transposed words: wT[j*768 + col] bit l = (W[col][j*64+l] >= 0)
// ---------------------------------------------------------------------------
__global__ void k_pack_wT(const float* __restrict__ W, unsigned long long* __restrict__ wT) {
    int idx = blockIdx.x * 256 + threadIdx.x;
    if (idx >= NH * NW) return;
    int col = idx / NW, j = idx % NW;
    unsigned long long w = 0ull;
    for (int l = 0; l < 64; ++l) {
        float v = W[(size_t)col * NH + j * 64 + l];
        w |= (unsigned long long)(v >= 0.0f ? 1 : 0) << l;
    }
    wT[(size_t)j * NH + col] = w;
}

// ---------------------------------------------------------------------------
// GEMM1 replicating numpy einsum sum_of_products_contig_two (AVX512 npyv),
// restructured for FMA density:
//  - w tile (64 cols x 784) as bf16 +/-1 in LDS, unpack = 1 VALU op/elem
//  - x tile (16 rows x 784 f32) in LDS, broadcast reads
//  - chain order EXACT: a[g][j] accumulates k = t*64+g*16+j (t ascending),
//    tail k=768+i into group 0, combine (a0+a1)+(a2+a3), tree 8/4/2/1.
// Block: 1024 thr = 16 waves; wave = one batch row, lanes = 64 cols (chunk).
// ---------------------------------------------------------------------------
__global__ __launch_bounds__(1024, 4)
void k_gemm1_bf(const float* __restrict__ x, const unsigned short* __restrict__ wbf,
                const float* __restrict__ bnp,
                unsigned long long* __restrict__ s1p) {
    __shared__ float xs[16][ND];                    // 50,176 B
    __shared__ alignas(16) unsigned short wl[64][800];  // 102,400 B (pitch 800: 2-way bank alias only)
    const int tid = threadIdx.x;
    const int r0 = blockIdx.x * 16;
    const int c0 = blockIdx.y * 64;

    // stage x: 16 rows x 784 f32
    for (int d = tid; d < 16 * ND; d += 1024) {
        int r = d / ND, k = d % ND;
        xs[r][k] = x[(size_t)(r0 + r) * ND + k];
    }
    // stage w: 64 cols x 784 bf16 (392 dwords per col)
    const unsigned int* wsrc = (const unsigned int*)wbf;
    for (int d = tid; d < 64 * 392; d += 1024) {
        int c = d / 392, k2 = d % 392;
        ((unsigned int*)&wl[c][0])[k2] = wsrc[(size_t)(c0 + c) * 392 + k2];
    }
    __syncthreads();

    const int wave = tid >> 6, lane = tid & 63;
    const unsigned short* wrow = &wl[lane][0];
    const float* xrow = &xs[wave][0];

    float a[4][16];
#pragma unroll
    for (int g = 0; g < 4; ++g)
#pragma unroll
        for (int i = 0; i < 16; ++i) a[g][i] = 0.0f;

    // main loop: t = 0..11, each covers k = t*64 .. t*64+63
    for (int t = 0; t < 12; ++t) {
#pragma unroll
        for (int g = 0; g < 4; ++g) {
            const int k16 = t * 64 + g * 16;
            uint4 wA = *(const uint4*)(wrow + k16);       // 8 bf16 (k16..k16+7)
            uint4 wB = *(const uint4*)(wrow + k16 + 8);   // 8 bf16 (k16+8..k16+15)
            float4 x0 = *(const float4*)(xrow + k16);
            float4 x1 = *(const float4*)(xrow + k16 + 4);
            float4 x2 = *(const float4*)(xrow + k16 + 8);
            float4 x3 = *(const float4*)(xrow + k16 + 12);
            unsigned int dw[8] = {wA.x, wA.y, wA.z, wA.w, wB.x, wB.y, wB.z, wB.w};
            float wf[16];
#pragma unroll
            for (int p = 0; p < 8; ++p) {
                wf[2 * p]     = __uint_as_float(dw[p] << 16);          // low bf16 -> f32
                wf[2 * p + 1] = __uint_as_float(dw[p] & 0xFFFF0000u);  // high bf16 -> f32
            }
            float xv[16] = {x0.x, x0.y, x0.z, x0.w, x1.x, x1.y, x1.z, x1.w,
                            x2.x, x2.y, x2.z, x2.w, x3.x, x3.y, x3.z, x3.w};
#pragma unroll
            for (int j = 0; j < 16; ++j)
                a[g][j] = __fmaf_rn(wf[j], xv[j], a[g][j]);
        }
    }
    // single-vector tail: k = 768..783 into group 0
    {
        const int k16 = 768;
        uint4 wA = *(const uint4*)(wrow + k16);
        uint4 wB = *(const uint4*)(wrow + k16 + 8);
        float4 x0 = *(const float4*)(xrow + k16);
        float4 x1 = *(const float4*)(xrow + k16 + 4);
        float4 x2 = *(const float4*)(xrow + k16 + 8);
        float4 x3 = *(const float4*)(xrow + k16 + 12);
        unsigned int dw[8] = {wA.x, wA.y, wA.z, wA.w, wB.x, wB.y, wB.z, wB.w};
        float wf[16];
#pragma unroll
        for (int p = 0; p < 8; ++p) {
            wf[2 * p]     = __uint_as_float(dw[p] << 16);
            wf[2 * p + 1] = __uint_as_float(dw[p] & 0xFFFF0000u);
        }
        float xv[16] = {x0.x, x0.y, x0.z, x0.w, x1.x, x1.y, x1.z, x1.w,
                        x2.x, x2.y, x2.z, x2.w, x3.x, x3.y, x3.z, x3.w};
#pragma unroll
        for (int j = 0; j < 16; ++j)
            a[0][j] = __fmaf_rn(wf[j], xv[j], a[0][j]);
    }

    // combine: (a0+a1)+(a2+a3) lane-wise, then horizontal tree 8/4/2/1
    float v[16];
#pragma unroll
    for (int i = 0; i < 16; ++i)
        v[i] = __fadd_rn(__fadd_rn(a[0][i], a[1][i]), __fadd_rn(a[2][i], a[3][i]));
    float h8[8], h4[4], h2[2];
#pragma unroll
    for (int i = 0; i < 8; ++i) h8[i] = __fadd_rn(v[i], v[i + 8]);
#pragma unroll
    for (int i = 0; i < 4; ++i) h4[i] = __fadd_rn(h8[i], h8[i + 4]);
#pragma unroll
    for (int i = 0; i < 2; ++i) h2[i] = __fadd_rn(h4[i], h4[i + 2]);
    float acc = __fadd_rn(h2[0], h2[1]);

    // epilogue: + b1, BN1 f32 op-by-op, sign -> packed bits
    const int col = c0 + lane;
    const float sc = bnp[col], mm = bnp[NH + col], be = bnp[2 * NH + col],
                bias = bnp[3 * NH + col];
    float h  = __fadd_rn(acc, bias);
    float t1 = __fsub_rn(h, mm);
    float u  = __fmul_rn(t1, sc);
    float hb = __fadd_rn(u, be);
    unsigned long long word = __ballot(hb >= 0.0f);
    if (lane == 0) s1p[(size_t)(r0 + wave) * NW + blockIdx.y] = word;
}

// ---------------------------------------------------------------------------
// Binary layers 2/3: dot = 768 - 2*popcount(a XOR w) — exact integer, matches
// any-order f32 evaluation of +/-1 GEMM bit-for-bit (all partials exact).
// Epilogue faithful f32: h = fl(dot + b), BN op-by-op.
// MODE 0: sign -> packed bits. MODE 1: hardtanh -> f32 out.
// ---------------------------------------------------------------------------
template <int MODE>
__global__ __launch_bounds__(256, 2)
void k_popbin(const unsigned long long* __restrict__ Ap,
              const unsigned long long* __restrict__ wT,
              const float* __restrict__ bnp,
              unsigned long long* __restrict__ Sp, float* __restrict__ h_out) {
    __shared__ unsigned long long as[64][NW];
    const int tid = threadIdx.x;
    const int b0 = blockIdx.x * 64;

    for (int i = tid; i < 64 * NW; i += 256)
        as[i / NW][i % NW] = Ap[(size_t)(b0 + i / NW) * NW + i % NW];
    __syncthreads();

    const int wave = tid >> 6, lane = tid & 63;

    for (int chunk = 0; chunk < NW; ++chunk) {
        const int col = chunk * 64 + lane;
        unsigned long long w[NW];
#pragma unroll
        for (int j = 0; j < NW; ++j) w[j] = wT[(size_t)j * NH + col];
        const float sc = bnp[col], mm = bnp[NH + col], be = bnp[2 * NH + col],
                    bias = bnp[3 * NH + col];
        for (int r = 0; r < 16; ++r) {
            const int row = wave * 16 + r;
            int d = 0;
#pragma unroll
            for (int j = 0; j < NW; ++j)
                d += __builtin_popcountll(as[row][j] ^ w[j]);
            int dot = NH - 2 * d;
            float h  = __fadd_rn((float)dot, bias);
            float t  = __fsub_rn(h, mm);
            float u  = __fmul_rn(t, sc);
            float hb = __fadd_rn(u, be);
            if (MODE == 0) {
                unsigned long long word = __ballot(hb >= 0.0f);
                if (lane == 0) Sp[(size_t)(b0 + row) * NW + chunk] = word;
            } else {
                float hc = fminf(fmaxf(hb, -1.0f), 1.0f);
                h_out[(size_t)(b0 + row) * NH + col] = hc;
            }
        }
    }
}

// ---------------------------------------------------------------------------
// fc4 + log_softmax: one wave per row, double accumulation + shuffle reduce
// (no binarization downstream; 1e-6-level diffs vs f32 ref are far under threshold)
// ---------------------------------------------------------------------------
__global__ __launch_bounds__(256, 4)
void k_fc4(const float* __restrict__ h3, const float* __restrict__ W4,
           const float* __restrict__ b4, float* __restrict__ out) {
    __shared__ float w4s[NC * NH];
    const int tid = threadIdx.x;
    for (int i = tid; i < NC * NH; i += 256) w4s[i] = W4[i];
    __syncthreads();

    const int wave = tid >> 6, lane = tid & 63;
    const int row = blockIdx.x * 4 + wave;
    const float* hrow = h3 + (size_t)row * NH;

    double p[NC];
#pragma unroll
    for (int c = 0; c < NC; ++c) p[c] = 0.0;

    for (int it = 0; it < NH / 64; ++it) {
        int j = it * 64 + lane;
        double hv = (double)hrow[j];
#pragma unroll
        for (int c = 0; c < NC; ++c) p[c] += hv * (double)w4s[c * NH + j];
    }
#pragma unroll
    for (int c = 0; c < NC; ++c) {
#pragma unroll
        for (int off = 32; off > 0; off >>= 1) p[c] += __shfl_xor(p[c], off, 64);
    }
    double lg[NC];
    double mx = -1e300;
#pragma unroll
    for (int c = 0; c < NC; ++c) {
        lg[c] = p[c] + (double)b4[c];
        mx = fmax(mx, lg[c]);
    }
    double s = 0.0;
#pragma unroll
    for (int c = 0; c < NC; ++c) s += exp(lg[c] - mx);
    double lse = mx + log(s);
    if (lane < NC) {
        double v = 0.0;
#pragma unroll
        for (int c = 0; c < NC; ++c)
            if (lane == c) v = lg[c];
        out[(size_t)row * NC + lane] = (float)(v - lse);
    }
}

// ---------------------------------------------------------------------------
// launch
// ---------------------------------------------------------------------------
extern "C" void kernel_launch(void* const* d_in, const int* in_sizes, int n_in,
                              void* d_out, int out_size, void* d_ws, size_t ws_size,
                              hipStream_t stream) {
    const float* x  = (const float*)d_in[0];
    const float* W1 = (const float*)d_in[1];
    const float* b1 = (const float*)d_in[2];
    const float* W2 = (const float*)d_in[3];
    const float* b2 = (const float*)d_in[4];
    const float* W3 = (const float*)d_in[5];
    const float* b3 = (const float*)d_in[6];
    const float* W4 = (const float*)d_in[7];
    const float* b4 = (const float*)d_in[8];
    const float* g1 = (const float*)d_in[9],  *be1 = (const float*)d_in[10];
    const float* m1 = (const float*)d_in[11], *v1  = (const float*)d_in[12];
    const float* g2 = (const float*)d_in[13], *be2 = (const float*)d_in[14];
    const float* m2 = (const float*)d_in[15], *v2  = (const float*)d_in[16];
    const float* g3 = (const float*)d_in[17], *be3 = (const float*)d_in[18];
    const float* m3 = (const float*)d_in[19], *v3  = (const float*)d_in[20];
    float* out = (float*)d_out;

    char* ws = (char*)d_ws;
    size_t off = 0;
    unsigned short* wbf = (unsigned short*)(ws + off);  off += (size_t)NH * ND * 2;   // 1,204,224
    unsigned long long* w2pT = (unsigned long long*)(ws + off); off += (size_t)NW * NH * 8;  // 73,728
    unsigned long long* w3pT = (unsigned long long*)(ws + off); off += (size_t)NW * NH * 8;
    unsigned long long* s1p  = (unsigned long long*)(ws + off); off += (size_t)NB * NW * 8;  // 1,572,864
    unsigned long long* s2p  = (unsigned long long*)(ws + off); off += (size_t)NB * NW * 8;
    float*  h3   = (float*)(ws + off);              off += (size_t)NB * NH * 4;       // 50,331,648
    float* bnp1 = (float*)(ws + off);               off += (size_t)4 * NH * 4;
    float* bnp2 = (float*)(ws + off);               off += (size_t)4 * NH * 4;
    float* bnp3 = (float*)(ws + off);               off += (size_t)4 * NH * 4;
    (void)ws_size; (void)in_sizes; (void)n_in; (void)out_size;

    // prep
    k_pack_w1bf<<<dim3(4, NH), 256, 0, stream>>>(W1, wbf);
    k_pack_wT<<<dim3((NH * NW + 255) / 256), 256, 0, stream>>>(W2, w2pT);
    k_pack_wT<<<dim3((NH * NW + 255) / 256), 256, 0, stream>>>(W3, w3pT);
    k_bnprep_f32<<<dim3(3), 256, 0, stream>>>(g1, be1, m1, v1, b1, bnp1);
    k_bnprep_f32<<<dim3(3), 256, 0, stream>>>(g2, be2, m2, v2, b2, bnp2);
    k_bnprep_f32<<<dim3(3), 256, 0, stream>>>(g3, be3, m3, v3, b3, bnp3);

    // layers
    k_gemm1_bf<<<dim3(NB / 16, NH / 64), 1024, 0, stream>>>(x, wbf, bnp1, s1p);
    k_popbin<0><<<dim3(NB / 64), 256, 0, stream>>>(s1p, w2pT, bnp2, s2p, nullptr);
    k_popbin<1><<<dim3(NB / 64), 256, 0, stream>>>(s2p, w3pT, bnp3, nullptr, h3);
    k_fc4<<<dim3(NB / 4), 256, 0, stream>>>(h3, W4, b4, out);
}

// Round 7
// 1140.179 us; speedup vs baseline: 1.8221x; 1.2670x over previous
//
#include <hip/hip_runtime.h>
#include <math.h>
#include <stdint.h>

// Problem dims
#define NB 16384    // batch
#define NH 768      // hidden
#define ND 784      // input features
#define NC 10       // classes
#define NW 12       // u64 words per 768-bit row

// ---------------------------------------------------------------------------
// prep: BN params in FAITHFUL f32 (replicating np op-by-op):
// sc = g * (1 / sqrt(v + 1e-5)), each op f32-rounded. [0]=sc,[1]=m,[2]=be,[3]=bias
// ---------------------------------------------------------------------------
__global__ void k_bnprep_f32(const float* __restrict__ g, const float* __restrict__ be,
                             const float* __restrict__ m, const float* __restrict__ v,
                             const float* __restrict__ bias, float* __restrict__ out) {
    int i = blockIdx.x * 256 + threadIdx.x;
    if (i >= NH) return;
    float t1 = __fadd_rn(v[i], 1e-5f);
    float t2 = __fsqrt_rn(t1);
    float t3 = __fdiv_rn(1.0f, t2);
    out[i]          = __fmul_rn(g[i], t3);
    out[NH + i]     = m[i];
    out[2 * NH + i] = be[i];
    out[3 * NH + i] = bias[i];
}

// ---------------------------------------------------------------------------
// prep: W1 signs as bf16 +/-1 bit patterns (0x3F80 / 0xBF80), row-major [col][k]
// ---------------------------------------------------------------------------
__global__ void k_pack_w1bf(const float* __restrict__ W1, unsigned short* __restrict__ wbf) {
    int k = blockIdx.x * 256 + threadIdx.x;
    int col = blockIdx.y;
    if (k >= ND) return;
    float v = W1[(size_t)col * ND + k];
    wbf[(size_t)col * ND + k] = (v >= 0.0f) ? (unsigned short)0x3F80 : (unsigned short)0xBF80;
}

// ---------------------------------------------------------------------------
// prep: W2/W3 sign bits, transposed words: wT[j*768 + col] bit l = (W[col][j*64+l] >= 0)
// ---------------------------------------------------------------------------
__global__ void k_pack_wT(const float* __restrict__ W, unsigned long long* __restrict__ wT) {
    int idx = blockIdx.x * 256 + threadIdx.x;
    if (idx >= NH * NW) return;
    int col = idx / NW, j = idx % NW;
    unsigned long long w = 0ull;
    for (int l = 0; l < 64; ++l) {
        float v = W[(size_t)col * NH + j * 64 + l];
        w |= (unsigned long long)(v >= 0.0f ? 1 : 0) << l;
    }
    wT[(size_t)j * NH + col] = w;
}

// ---------------------------------------------------------------------------
// GEMM1 replicating numpy einsum sum_of_products_contig_two (AVX512 npyv).
// Chain order EXACT: a[g][j] accumulates k = t*64+g*16+j (t ascending),
// tail k=768+i into group 0, combine (a0+a1)+(a2+a3), tree 8/4/2/1.
// R7 changes vs R6 (math identical):
//  - wl pitch 808 shorts = 1616 B = 16*101 (101 odd): lane L's b128 read starts
//    at bank-block (5L mod 8) -> uniform 8 lanes/block, zero excess conflicts
//    (R6 pitch 1600 B gave 32-way conflicts: 2.3e8 SQ_LDS_BANK_CONFLICT).
//  - amdgpu_waves_per_eu(4,4): pin 4 waves/EU -> 128-VGPR budget, no scratch
//    spills (R6: VGPR_Count=64, 253 MB spill WRITE_SIZE).
// Block: 1024 thr = 16 waves; wave = one batch row, lanes = 64 cols (chunk).
// ---------------------------------------------------------------------------
__global__ __launch_bounds__(1024, 4) __attribute__((amdgpu_waves_per_eu(4, 4)))
void k_gemm1_bf(const float* __restrict__ x, const unsigned short* __restrict__ wbf,
                const float* __restrict__ bnp,
                unsigned long long* __restrict__ s1p) {
    __shared__ float xs[16][ND];                        // 50,176 B
    __shared__ alignas(16) unsigned short wl[64][808];  // 103,424 B (pitch 1616 B, p16=101 odd)
    const int tid = threadIdx.x;
    const int r0 = blockIdx.x * 16;
    const int c0 = blockIdx.y * 64;

    // stage x: 16 rows x 784 f32
    for (int d = tid; d < 16 * ND; d += 1024) {
        int r = d / ND, k = d % ND;
        xs[r][k] = x[(size_t)(r0 + r) * ND + k];
    }
    // stage w: 64 cols x 784 bf16 (392 dwords per col); 16 threads per col
    {
        const unsigned int* wsrc = (const unsigned int*)wbf;
        int c = tid >> 4;          // 0..63
        int q = tid & 15;
        unsigned int* dst = (unsigned int*)&wl[c][0];
        const unsigned int* srcp = wsrc + (size_t)(c0 + c) * 392;
        for (int k2 = q; k2 < 392; k2 += 16) dst[k2] = srcp[k2];
    }
    __syncthreads();

    const int wave = tid >> 6, lane = tid & 63;
    const unsigned short* wrow = &wl[lane][0];
    const float* xrow = &xs[wave][0];

    float a[4][16];
#pragma unroll
    for (int g = 0; g < 4; ++g)
#pragma unroll
        for (int i = 0; i < 16; ++i) a[g][i] = 0.0f;

    // main loop: t = 0..11, each covers k = t*64 .. t*64+63
    for (int t = 0; t < 12; ++t) {
#pragma unroll
        for (int g = 0; g < 4; ++g) {
            const int k16 = t * 64 + g * 16;
            uint4 wA = *(const uint4*)(wrow + k16);       // 8 bf16 (k16..k16+7)
            uint4 wB = *(const uint4*)(wrow + k16 + 8);   // 8 bf16 (k16+8..k16+15)
            float4 x0 = *(const float4*)(xrow + k16);
            float4 x1 = *(const float4*)(xrow + k16 + 4);
            float4 x2 = *(const float4*)(xrow + k16 + 8);
            float4 x3 = *(const float4*)(xrow + k16 + 12);
            unsigned int dw[8] = {wA.x, wA.y, wA.z, wA.w, wB.x, wB.y, wB.z, wB.w};
            float wf[16];
#pragma unroll
            for (int p = 0; p < 8; ++p) {
                wf[2 * p]     = __uint_as_float(dw[p] << 16);          // low bf16 -> f32
                wf[2 * p + 1] = __uint_as_float(dw[p] & 0xFFFF0000u);  // high bf16 -> f32
            }
            float xv[16] = {x0.x, x0.y, x0.z, x0.w, x1.x, x1.y, x1.z, x1.w,
                            x2.x, x2.y, x2.z, x2.w, x3.x, x3.y, x3.z, x3.w};
#pragma unroll
            for (int j = 0; j < 16; ++j)
                a[g][j] = __fmaf_rn(wf[j], xv[j], a[g][j]);
        }
    }
    // single-vector tail: k = 768..783 into group 0
    {
        const int k16 = 768;
        uint4 wA = *(const uint4*)(wrow + k16);
        uint4 wB = *(const uint4*)(wrow + k16 + 8);
        float4 x0 = *(const float4*)(xrow + k16);
        float4 x1 = *(const float4*)(xrow + k16 + 4);
        float4 x2 = *(const float4*)(xrow + k16 + 8);
        float4 x3 = *(const float4*)(xrow + k16 + 12);
        unsigned int dw[8] = {wA.x, wA.y, wA.z, wA.w, wB.x, wB.y, wB.z, wB.w};
        float wf[16];
#pragma unroll
        for (int p = 0; p < 8; ++p) {
            wf[2 * p]     = __uint_as_float(dw[p] << 16);
            wf[2 * p + 1] = __uint_as_float(dw[p] & 0xFFFF0000u);
        }
        float xv[16] = {x0.x, x0.y, x0.z, x0.w, x1.x, x1.y, x1.z, x1.w,
                        x2.x, x2.y, x2.z, x2.w, x3.x, x3.y, x3.z, x3.w};
#pragma unroll
        for (int j = 0; j < 16; ++j)
            a[0][j] = __fmaf_rn(wf[j], xv[j], a[0][j]);
    }

    // combine: (a0+a1)+(a2+a3) lane-wise, then horizontal tree 8/4/2/1
    float v[16];
#pragma unroll
    for (int i = 0; i < 16; ++i)
        v[i] = __fadd_rn(__fadd_rn(a[0][i], a[1][i]), __fadd_rn(a[2][i], a[3][i]));
    float h8[8], h4[4], h2[2];
#pragma unroll
    for (int i = 0; i < 8; ++i) h8[i] = __fadd_rn(v[i], v[i + 8]);
#pragma unroll
    for (int i = 0; i < 4; ++i) h4[i] = __fadd_rn(h8[i], h8[i + 4]);
#pragma unroll
    for (int i = 0; i < 2; ++i) h2[i] = __fadd_rn(h4[i], h4[i + 2]);
    float acc = __fadd_rn(h2[0], h2[1]);

    // epilogue: + b1, BN1 f32 op-by-op, sign -> packed bits
    const int col = c0 + lane;
    const float sc = bnp[col], mm = bnp[NH + col], be = bnp[2 * NH + col],
                bias = bnp[3 * NH + col];
    float h  = __fadd_rn(acc, bias);
    float t1 = __fsub_rn(h, mm);
    float u  = __fmul_rn(t1, sc);
    float hb = __fadd_rn(u, be);
    unsigned long long word = __ballot(hb >= 0.0f);
    if (lane == 0) s1p[(size_t)(r0 + wave) * NW + blockIdx.y] = word;
}

// ---------------------------------------------------------------------------
// Binary layers 2/3: dot = 768 - 2*popcount(a XOR w) — exact integer, matches
// any-order f32 evaluation of +/-1 GEMM bit-for-bit (all partials exact).
// Epilogue faithful f32: h = fl(dot + b), BN op-by-op.
// MODE 0: sign -> packed bits. MODE 1: hardtanh -> f32 out.
// ---------------------------------------------------------------------------
template <int MODE>
__global__ __launch_bounds__(256, 2)
void k_popbin(const unsigned long long* __restrict__ Ap,
              const unsigned long long* __restrict__ wT,
              const float* __restrict__ bnp,
              unsigned long long* __restrict__ Sp, float* __restrict__ h_out) {
    __shared__ unsigned long long as[64][NW];
    const int tid = threadIdx.x;
    const int b0 = blockIdx.x * 64;

    for (int i = tid; i < 64 * NW; i += 256)
        as[i / NW][i % NW] = Ap[(size_t)(b0 + i / NW) * NW + i % NW];
    __syncthreads();

    const int wave = tid >> 6, lane = tid & 63;

    for (int chunk = 0; chunk < NW; ++chunk) {
        const int col = chunk * 64 + lane;
        unsigned long long w[NW];
#pragma unroll
        for (int j = 0; j < NW; ++j) w[j] = wT[(size_t)j * NH + col];
        const float sc = bnp[col], mm = bnp[NH + col], be = bnp[2 * NH + col],
                    bias = bnp[3 * NH + col];
        for (int r = 0; r < 16; ++r) {
            const int row = wave * 16 + r;
            int d = 0;
#pragma unroll
            for (int j = 0; j < NW; ++j)
                d += __builtin_popcountll(as[row][j] ^ w[j]);
            int dot = NH - 2 * d;
            float h  = __fadd_rn((float)dot, bias);
            float t  = __fsub_rn(h, mm);
            float u  = __fmul_rn(t, sc);
            float hb = __fadd_rn(u, be);
            if (MODE == 0) {
                unsigned long long word = __ballot(hb >= 0.0f);
                if (lane == 0) Sp[(size_t)(b0 + row) * NW + chunk] = word;
            } else {
                float hc = fminf(fmaxf(hb, -1.0f), 1.0f);
                h_out[(size_t)(b0 + row) * NH + col] = hc;
            }
        }
    }
}

// ---------------------------------------------------------------------------
// fc4 + log_softmax: one wave per row, double accumulation + shuffle reduce
// (no binarization downstream; 1e-6-level diffs vs f32 ref are far under threshold)
// ---------------------------------------------------------------------------
__global__ __launch_bounds__(256, 4)
void k_fc4(const float* __restrict__ h3, const float* __restrict__ W4,
           const float* __restrict__ b4, float* __restrict__ out) {
    __shared__ float w4s[NC * NH];
    const int tid = threadIdx.x;
    for (int i = tid; i < NC * NH; i += 256) w4s[i] = W4[i];
    __syncthreads();

    const int wave = tid >> 6, lane = tid & 63;
    const int row = blockIdx.x * 4 + wave;
    const float* hrow = h3 + (size_t)row * NH;

    double p[NC];
#pragma unroll
    for (int c = 0; c < NC; ++c) p[c] = 0.0;

    for (int it = 0; it < NH / 64; ++it) {
        int j = it * 64 + lane;
        double hv = (double)hrow[j];
#pragma unroll
        for (int c = 0; c < NC; ++c) p[c] += hv * (double)w4s[c * NH + j];
    }
#pragma unroll
    for (int c = 0; c < NC; ++c) {
#pragma unroll
        for (int off = 32; off > 0; off >>= 1) p[c] += __shfl_xor(p[c], off, 64);
    }
    double lg[NC];
    double mx = -1e300;
#pragma unroll
    for (int c = 0; c < NC; ++c) {
        lg[c] = p[c] + (double)b4[c];
        mx = fmax(mx, lg[c]);
    }
    double s = 0.0;
#pragma unroll
    for (int c = 0; c < NC; ++c) s += exp(lg[c] - mx);
    double lse = mx + log(s);
    if (lane < NC) {
        double v = 0.0;
#pragma unroll
        for (int c = 0; c < NC; ++c)
            if (lane == c) v = lg[c];
        out[(size_t)row * NC + lane] = (float)(v - lse);
    }
}

// ---------------------------------------------------------------------------
// launch
// ---------------------------------------------------------------------------
extern "C" void kernel_launch(void* const* d_in, const int* in_sizes, int n_in,
                              void* d_out, int out_size, void* d_ws, size_t ws_size,
                              hipStream_t stream) {
    const float* x  = (const float*)d_in[0];
    const float* W1 = (const float*)d_in[1];
    const float* b1 = (const float*)d_in[2];
    const float* W2 = (const float*)d_in[3];
    const float* b2 = (const float*)d_in[4];
    const float* W3 = (const float*)d_in[5];
    const float* b3 = (const float*)d_in[6];
    const float* W4 = (const float*)d_in[7];
    const float* b4 = (const float*)d_in[8];
    const float* g1 = (const float*)d_in[9],  *be1 = (const float*)d_in[10];
    const float* m1 = (const float*)d_in[11], *v1  = (const float*)d_in[12];
    const float* g2 = (const float*)d_in[13], *be2 = (const float*)d_in[14];
    const float* m2 = (const float*)d_in[15], *v2  = (const float*)d_in[16];
    const float* g3 = (const float*)d_in[17], *be3 = (const float*)d_in[18];
    const float* m3 = (const float*)d_in[19], *v3  = (const float*)d_in[20];
    float* out = (float*)d_out;

    char* ws = (char*)d_ws;
    size_t off = 0;
    unsigned short* wbf = (unsigned short*)(ws + off);  off += (size_t)NH * ND * 2;   // 1,204,224
    unsigned long long* w2pT = (unsigned long long*)(ws + off); off += (size_t)NW * NH * 8;  // 73,728
    unsigned long long* w3pT = (unsigned long long*)(ws + off); off += (size_t)NW * NH * 8;
    unsigned long long* s1p  = (unsigned long long*)(ws + off); off += (size_t)NB * NW * 8;  // 1,572,864
    unsigned long long* s2p  = (unsigned long long*)(ws + off); off += (size_t)NB * NW * 8;
    float*  h3   = (float*)(ws + off);              off += (size_t)NB * NH * 4;       // 50,331,648
    float* bnp1 = (float*)(ws + off);               off += (size_t)4 * NH * 4;
    float* bnp2 = (float*)(ws + off);               off += (size_t)4 * NH * 4;
    float* bnp3 = (float*)(ws + off);               off += (size_t)4 * NH * 4;
    (void)ws_size; (void)in_sizes; (void)n_in; (void)out_size;

    // prep
    k_pack_w1bf<<<dim3(4, NH), 256, 0, stream>>>(W1, wbf);
    k_pack_wT<<<dim3((NH * NW + 255) / 256), 256, 0, stream>>>(W2, w2pT);
    k_pack_wT<<<dim3((NH * NW + 255) / 256), 256, 0, stream>>>(W3, w3pT);
    k_bnprep_f32<<<dim3(3), 256, 0, stream>>>(g1, be1, m1, v1, b1, bnp1);
    k_bnprep_f32<<<dim3(3), 256, 0, stream>>>(g2, be2, m2, v2, b2, bnp2);
    k_bnprep_f32<<<dim3(3), 256, 0, stream>>>(g3, be3, m3, v3, b3, bnp3);

    // layers
    k_gemm1_bf<<<dim3(NB / 16, NH / 64), 1024, 0, stream>>>(x, wbf, bnp1, s1p);
    k_popbin<0><<<dim3(NB / 64), 256, 0, stream>>>(s1p, w2pT, bnp2, s2p, nullptr);
    k_popbin<1><<<dim3(NB / 64), 256, 0, stream>>>(s2p, w3pT, bnp3, nullptr, h3);
    k_fc4<<<dim3(NB / 4), 256, 0, stream>>>(h3, W4, b4, out);
}